// Round 8
// baseline (93.592 us; speedup 1.0000x reference)
//
#include <hip/hip_runtime.h>

#define PNUM 512
#define LB   512   // L_PREDS * BATCH

// smooth_l1 for one (x,y) point pair, split accumulators.
// sl1(x) = t*(|x| - 0.5t), t = min(|x|,1) — 4 VALU/comp if abs folds to modifiers.
#define SL1(px, py, qx, qy, accA, accB) {                        \
    float dx_ = (px) - (qx), dy_ = (py) - (qy);                  \
    float tx_ = fminf(fabsf(dx_), 1.0f);                         \
    float ty_ = fminf(fabsf(dy_), 1.0f);                         \
    accA = fmaf(tx_, fmaf(-0.5f, tx_, fabsf(dx_)), accA);        \
    accB = fmaf(ty_, fmaf(-0.5f, ty_, fabsf(dy_)), accB); }

// One s-step: 8 shifts x 2 j = 16 point evals. Window W0..W4 = 5 consecutive
// gt float4s (10 points); Pv = pred float4 (2 points, j even/odd).
#define BODY(Pv, W0, W1, W2, W3, W4)                             \
    SL1((Pv).x,(Pv).y,(W0).x,(W0).y,a0,b0);                      \
    SL1((Pv).z,(Pv).w,(W0).z,(W0).w,a0,b0);                      \
    SL1((Pv).x,(Pv).y,(W0).z,(W0).w,a1,b1);                      \
    SL1((Pv).z,(Pv).w,(W1).x,(W1).y,a1,b1);                      \
    SL1((Pv).x,(Pv).y,(W1).x,(W1).y,a2,b2);                      \
    SL1((Pv).z,(Pv).w,(W1).z,(W1).w,a2,b2);                      \
    SL1((Pv).x,(Pv).y,(W1).z,(W1).w,a3,b3);                      \
    SL1((Pv).z,(Pv).w,(W2).x,(W2).y,a3,b3);                      \
    SL1((Pv).x,(Pv).y,(W2).x,(W2).y,a4,b4);                      \
    SL1((Pv).z,(Pv).w,(W2).z,(W2).w,a4,b4);                      \
    SL1((Pv).x,(Pv).y,(W2).z,(W2).w,a5,b5);                      \
    SL1((Pv).z,(Pv).w,(W3).x,(W3).y,a5,b5);                      \
    SL1((Pv).x,(Pv).y,(W3).x,(W3).y,a6,b6);                      \
    SL1((Pv).z,(Pv).w,(W3).z,(W3).w,a6,b6);                      \
    SL1((Pv).x,(Pv).y,(W3).z,(W3).w,a7,b7);                      \
    SL1((Pv).z,(Pv).w,(W4).x,(W4).y,a7,b7);

// Block = (l,b). 8 waves; wave w owns j in [64w, 64w+64); lane l owns shifts
// 8l..8l+7. gt ring (1024 pts doubled) parity-split by float4-index mod 4.
// Fused finalize: last block (atomic ticket) reduces bmin -> out.
__global__ __launch_bounds__(512, 4)
void poly_match_kernel(const float* __restrict__ pred,   // (2,256,512,2)
                       const float* __restrict__ gt,     // (256,512,2)
                       float* __restrict__ bmin,         // (512,) in d_ws
                       int*   __restrict__ counter,      // 1 int in d_ws (zeroed per call)
                       float* __restrict__ out)          // scalar
{
    __shared__ float4 sg[4][132];     // parity-split doubled gt ring (+pads)
    __shared__ float4 spred[258];     // full pred, float4 view (+pad)
    __shared__ float  part2[64][64];  // [w*8+r][lane] per-wave shift partials
    __shared__ float  swave[8];
    __shared__ int    s_tic;

    const int lb = blockIdx.x;
    const int b  = lb & 255;
    const int t  = threadIdx.x;       // 0..511
    const int w  = t >> 6;            // wave 0..7
    const int l  = t & 63;            // lane

    const float4* pp4 = (const float4*)(pred + (size_t)lb * PNUM * 2);
    const float4* gp4 = (const float4*)(gt   + (size_t)b  * PNUM * 2);

    // stage: ring_f4[m] = gt_f4[m & 255], m = t covers 0..511
    sg[t & 3][t >> 2] = gp4[t & 255];
    if (t < 8)   sg[t & 3][128 + (t >> 2)] = gp4[t];   // pads k=128,129
    if (t < 256) spred[t] = pp4[t];
    if (t == 0)  spred[256] = pp4[0];                  // dead-prefetch pad
    __syncthreads();

    const int A  = l + 8 * w;     // gather base: k index into sg[p][.]
    const int pb = 32 * w;        // pred float4 base for this wave's j-range

    float a0=0.f,a1=0.f,a2=0.f,a3=0.f,a4=0.f,a5=0.f,a6=0.f,a7=0.f;
    float b0=0.f,b1=0.f,b2=0.f,b3=0.f,b4=0.f,b5=0.f,b6=0.f,b7=0.f;

    float4 v0 = sg[0][A];
    float4 v1 = sg[1][A];
    float4 v2 = sg[2][A];
    float4 v3 = sg[3][A];
    float4 v4 = sg[0][A + 1];
    float4 P  = spred[pb];

    #pragma unroll 2
    for (int q = 0; q < 8; ++q) {   // s = 4q..4q+3; j advances 2 per s-step
        const float4 n0  = sg[1][A + q + 1];
        const float4 Pn  = spred[pb + 4 * q + 1];
        BODY(P, v0, v1, v2, v3, v4)

        const float4 n1  = sg[2][A + q + 1];
        const float4 Pn2 = spred[pb + 4 * q + 2];
        BODY(Pn, v1, v2, v3, v4, n0)

        const float4 n2  = sg[3][A + q + 1];
        const float4 Pn3 = spred[pb + 4 * q + 3];
        BODY(Pn2, v2, v3, v4, n0, n1)

        const float4 n3  = sg[0][A + q + 2];
        const float4 Pn4 = spred[pb + 4 * q + 4];
        BODY(Pn3, v3, v4, n0, n1, n2)

        v0 = v4; v1 = n0; v2 = n1; v3 = n2; v4 = n3; P = Pn4;
    }

    // per-wave j-partials: row w*8+r, col l  (lanes -> consecutive banks)
    part2[w * 8 + 0][l] = a0 + b0;
    part2[w * 8 + 1][l] = a1 + b1;
    part2[w * 8 + 2][l] = a2 + b2;
    part2[w * 8 + 3][l] = a3 + b3;
    part2[w * 8 + 4][l] = a4 + b4;
    part2[w * 8 + 5][l] = a5 + b5;
    part2[w * 8 + 6][l] = a6 + b6;
    part2[w * 8 + 7][l] = a7 + b7;
    __syncthreads();

    // combine: thread t handles shift i = 8*l2 + g (g = t>>6); fixed-order sum over w
    {
        const int g  = t >> 6;
        const int l2 = t & 63;
        float v = part2[g][l2];
        #pragma unroll
        for (int ww = 1; ww < 8; ++ww)
            v += part2[ww * 8 + g][l2];

        float m = v;
        #pragma unroll
        for (int d = 1; d < 64; d <<= 1)
            m = fminf(m, __shfl_xor(m, d, 64));

        if (l2 == 0) swave[g] = m;
    }
    __syncthreads();

    if (t == 0) {
        float mm = swave[0];
        #pragma unroll
        for (int k = 1; k < 8; ++k) mm = fminf(mm, swave[k]);
        // release-store result, then take a ticket (acq_rel RMW forms a
        // release sequence -> last block's add synchronizes with all)
        __hip_atomic_store(&bmin[lb], mm, __ATOMIC_RELEASE, __HIP_MEMORY_SCOPE_AGENT);
        s_tic = __hip_atomic_fetch_add(counter, 1, __ATOMIC_ACQ_REL, __HIP_MEMORY_SCOPE_AGENT);
    }
    __syncthreads();

    if (s_tic == LB - 1) {
        // last block: reduce all 512 bmin -> out (agent-scope acquire loads
        // bypass stale per-XCD caches)
        float v = __hip_atomic_load(&bmin[t], __ATOMIC_ACQUIRE, __HIP_MEMORY_SCOPE_AGENT);
        #pragma unroll
        for (int d = 1; d < 64; d <<= 1)
            v += __shfl_xor(v, d, 64);
        if ((t & 63) == 0) swave[t >> 6] = v;   // safe: sync above
        __syncthreads();
        if (t == 0) {
            float tot = 0.0f;
            #pragma unroll
            for (int k = 0; k < 8; ++k) tot += swave[k];
            out[0] = tot * (1.0f / (512.0f * 512.0f));
        }
    }
}

extern "C" void kernel_launch(void* const* d_in, const int* in_sizes, int n_in,
                              void* d_out, int out_size, void* d_ws, size_t ws_size,
                              hipStream_t stream)
{
    const float* pred = (const float*)d_in[0];  // (2,256,512,2) fp32
    const float* gt   = (const float*)d_in[1];  // (256,512,2)   fp32
    float* out     = (float*)d_out;             // scalar fp32
    float* bmin    = (float*)d_ws;              // 512 floats
    int*   counter = (int*)((char*)d_ws + 2048);

    hipMemsetAsync(counter, 0, sizeof(int), stream);   // graph-capturable
    poly_match_kernel<<<LB, 512, 0, stream>>>(pred, gt, bmin, counter, out);
}